// Round 4
// baseline (130.568 us; speedup 1.0000x reference)
//
#include <hip/hip_runtime.h>

// net_86698209837440: N=100000, DEG=32 (edges sorted by tgt, deg==32), D=24, NK=2, H=64.
// R11 = R10 gang-gather with FULL-DEPTH load hoisting. R10's loop waited
// vmcnt(0) on gang g before issuing gang g+1 (effective depth-1): ~900cy HBM
// latency exposed per gang. Now all 16 gather dwordx4 (+8 xv u16) issue
// up-front; WRITE_GANG(gg) waits with counted vmcnt (12/8/4/0 via reg deps),
// so the wave pays ~one 900cy exposure total, then streams.
//  - G[4][4] i32x4 = 64 VGPR in-flight lines; __launch_bounds__(256,4) -> 128 cap.
//  - xcvt: fully-coalesced padded-row writes (u16x4 per chunk incl. zero pad).
// Math identical to R10 (same swizzle, fragments, epilogue).

#define NN   100000
#define DEG  32
#define EE   (NN * DEG)
#define DD   24
#define HH   64
#define NPB  32            // nodes per block; 100000 = 3125 * 32 exact
#define TPB  256
#define NPW  8             // nodes per wave (4 gangs of 2)
#define PST  56            // pre_s row stride (ushorts)
#define XRU  32            // padded xb row length in u16 (64 bytes)

typedef __attribute__((ext_vector_type(8)))  short short8;
typedef __attribute__((ext_vector_type(16))) float float16;
typedef __attribute__((ext_vector_type(4)))  float f32x4;
typedef __attribute__((ext_vector_type(4)))  int   i32x4;
typedef __attribute__((ext_vector_type(4)))  unsigned short u16x4;

__device__ __forceinline__ unsigned short f2bf(float f) {
    union { float f; unsigned u; } v; v.f = f;
    unsigned r = v.u + 0x7fffu + ((v.u >> 16) & 1u);   // RNE
    return (unsigned short)(r >> 16);
}

__device__ __forceinline__ float bf2f(unsigned u) {
    union { unsigned i; float f; } v; v.i = u << 16; return v.f;
}

// lo16(a) -> low half, lo16(b) -> high half, one v_perm_b32
__device__ __forceinline__ unsigned pk(unsigned a, unsigned b) {
    return __builtin_amdgcn_perm(b, a, 0x05040100u);
}

__device__ __forceinline__ short8 mk8(unsigned u0, unsigned u1, unsigned u2, unsigned u3) {
    union { unsigned u[4]; short8 s; } p;
    p.u[0] = u0; p.u[1] = u1; p.u[2] = u2; p.u[3] = u3;
    return p.s;
}

// ---- pre-pass: x fp32 [N][24] -> bf16 padded [N][32] (64B rows), coalesced
// writes over the full padded table (pad chunks 6,7 write zeros).
__global__ void xcvt(const float* __restrict__ x, unsigned short* __restrict__ xb, int n8) {
    int c = blockIdx.x * blockDim.x + threadIdx.x;   // u16x4 chunk in padded table
    if (c < n8) {
        const int row = c >> 3;
        const int pos = c & 7;
        u16x4 o = (u16x4){0, 0, 0, 0};
        if (pos < 6) {
            f32x4 v = __builtin_nontemporal_load(((const f32x4*)x) + row * 6 + pos);
            o.x = f2bf(v.x); o.y = f2bf(v.y); o.z = f2bf(v.z); o.w = f2bf(v.w);
        }
        ((u16x4*)xb)[c] = o;
    }
}

__global__ __launch_bounds__(TPB, 4) void gnn(
    const unsigned short* __restrict__ xb,   // [N,32] bf16 padded (gather table)
    const int*            __restrict__ ei,   // [2,E]; row 0 = src
    const float*          __restrict__ kv,   // [2,E]
    const float*          __restrict__ W,    // [64,48]
    float*                __restrict__ out)  // [N,64]
{
    __shared__ int            ei_s[NPB * DEG];       // 4 KB: src*64 byte offsets
    __shared__ unsigned short kv_s[2 * NPB * DEG];   // 4 KB bf16 kvals
    __shared__ unsigned short pre_s[NPB * PST];      // 3.5 KB bf16 pre rows
    __shared__ unsigned short xs_s[4][64 * XRU];     // 16 KB: per-wave gang tile

    const int t    = threadIdx.x;
    const int lane = t & 63;
    const int w    = t >> 6;
    const int m    = lane & 31;      // A-row / B-col / C-col
    const int kh   = lane >> 5;      // K-half
    const int kh8  = kh * 8;
    const int base = blockIdx.x * NPB;
    const int dclamp = (m < DD) ? m : (DD - 1);
    const int m2     = dclamp * 2;   // byte offset within row
    const char* xbc  = (const char*)xb;

    // gang-gather geometry (per lane)
    const int er   = lane >> 2;                        // edge-slot within 16
    const int q16  = (lane & 3) * 16;                  // 16B chunk within row
    char* xsb = (char*)&xs_s[w][0];                    // wave-private 4KB tile
    const unsigned wswz = (unsigned)((lane & 32) << 1);  // write xor: ((row&8)<<3)
    const unsigned fswz = (unsigned)(kh << 6);           // frag-read xor

    // ---- cooperative staging: ei row0 (pre-scaled *64) + both kv rows (bf16)
    {
        const size_t eb = (size_t)base * DEG;        // 1024 edges per block
        i32x4 ev = __builtin_nontemporal_load(((const i32x4*)(ei + eb)) + t);
        ev.x <<= 6; ev.y <<= 6; ev.z <<= 6; ev.w <<= 6;
        ((i32x4*)ei_s)[t] = ev;
        const f32x4 c0 = __builtin_nontemporal_load(((const f32x4*)(kv + eb)) + t);
        const f32x4 c1 = __builtin_nontemporal_load(((const f32x4*)(kv + EE + eb)) + t);
        u16x4 u0, u1;
        u0.x = f2bf(c0.x); u0.y = f2bf(c0.y); u0.z = f2bf(c0.z); u0.w = f2bf(c0.w);
        u1.x = f2bf(c1.x); u1.y = f2bf(c1.y); u1.z = f2bf(c1.z); u1.w = f2bf(c1.w);
        ((u16x4*)kv_s)[t] = u0;
        ((u16x4*)(kv_s + NPB * DEG))[t] = u1;
    }
    __syncthreads();

    // ================= Phase 1: full-depth gang pipeline =================
    const unsigned short* kvrow = kv_s + (m & 1) * (NPB * DEG);  // m=0 -> k0, m=1 -> k1

    i32x4 G[4][4];          // 64 VGPR of in-flight gathered lines
    unsigned xv8[NPW];      // epilogue x values, one per node

    // load 64 rows (2 nodes) of gathered x into regs; lanes 4k..4k+3 cover row k
    #define GATHER_GANG(gg) do {                                               \
        const int eb_ = (w * NPW + 2 * (gg)) * DEG;                            \
        const int o0_ = ei_s[eb_ +  0 + er];                                   \
        const int o1_ = ei_s[eb_ + 16 + er];                                   \
        const int o2_ = ei_s[eb_ + 32 + er];                                   \
        const int o3_ = ei_s[eb_ + 48 + er];                                   \
        G[gg][0] = *(const i32x4*)(xbc + (unsigned)(o0_ + q16));               \
        G[gg][1] = *(const i32x4*)(xbc + (unsigned)(o1_ + q16));               \
        G[gg][2] = *(const i32x4*)(xbc + (unsigned)(o2_ + q16));               \
        G[gg][3] = *(const i32x4*)(xbc + (unsigned)(o3_ + q16));               \
    } while (0)

    // write gang tile to LDS: row r = j*16+er at (r*64 + q16) ^ ((r&8)<<3)
    #define WRITE_GANG(gg) do {                                                \
        *(i32x4*)(xsb + (((0 * 1024) + er * 64 + q16) ^ wswz)) = G[gg][0];     \
        *(i32x4*)(xsb + (((1 * 1024) + er * 64 + q16) ^ wswz)) = G[gg][1];     \
        *(i32x4*)(xsb + (((2 * 1024) + er * 64 + q16) ^ wswz)) = G[gg][2];     \
        *(i32x4*)(xsb + (((3 * 1024) + er * 64 + q16) ^ wswz)) = G[gg][3];     \
    } while (0)

    #define COMPUTE_NODE(nn, gg) do {                                          \
        const int nl_ = w * NPW + 2 * (gg) + (nn);                             \
        const char* fb_ = xsb + (nn) * 2048 + (kh << 9);                       \
        unsigned ga_[8], gb_[8];                                               \
        _Pragma("unroll")                                                      \
        for (int j = 0; j < 8; ++j)                                            \
            ga_[j] = *(const unsigned short*)(fb_ + (((j << 6) + m2) ^ fswz)); \
        _Pragma("unroll")                                                      \
        for (int j = 0; j < 8; ++j)                                            \
            gb_[j] = *(const unsigned short*)(fb_ + 1024 + (((j << 6) + m2) ^ fswz)); \
        const int el_ = nl_ * DEG + kh8;                                       \
        const short8 raw0_ = *(const short8*)(kvrow + el_);                    \
        const short8 raw1_ = *(const short8*)(kvrow + el_ + 16);               \
        const unsigned fill_ = (m == 2) ? 0x3F803F80u : 0u;                    \
        const short8 af0_ = (m < 2) ? raw0_ : mk8(fill_, fill_, fill_, fill_); \
        const short8 af1_ = (m < 2) ? raw1_ : mk8(fill_, fill_, fill_, fill_); \
        const short8 bf0_ = mk8(pk(ga_[0], ga_[1]), pk(ga_[2], ga_[3]),        \
                                pk(ga_[4], ga_[5]), pk(ga_[6], ga_[7]));       \
        const short8 bf1_ = mk8(pk(gb_[0], gb_[1]), pk(gb_[2], gb_[3]),        \
                                pk(gb_[4], gb_[5]), pk(gb_[6], gb_[7]));       \
        float16 acc_;                                                          \
        _Pragma("unroll")                                                      \
        for (int r = 0; r < 16; ++r) acc_[r] = 0.f;                            \
        acc_ = __builtin_amdgcn_mfma_f32_32x32x16_bf16(af0_, bf0_, acc_, 0, 0, 0); \
        acc_ = __builtin_amdgcn_mfma_f32_32x32x16_bf16(af1_, bf1_, acc_, 0, 0, 0); \
        if (kh == 0 && m < DD) {                                               \
            const float sm_ = acc_[2] * (1.f / 32.f);                          \
            const float pv_ = bf2f(xv8[2 * (gg) + (nn)]) - sm_;                \
            pre_s[nl_ * PST + m]      = f2bf(acc_[0] + pv_);                   \
            pre_s[nl_ * PST + 24 + m] = f2bf(acc_[1] + pv_);                   \
        }                                                                      \
    } while (0)

    // all epilogue xv loads first (oldest in queue -> free by compute time)
    #pragma unroll
    for (int nn = 0; nn < NPW; ++nn)
        xv8[nn] = xb[(size_t)(base + w * NPW + nn) * XRU + dclamp];

    // all 16 gather dwordx4 in flight before any wait
    GATHER_GANG(0);
    GATHER_GANG(1);
    GATHER_GANG(2);
    GATHER_GANG(3);

    #pragma unroll
    for (int gg = 0; gg < NPW / 2; ++gg) {
        WRITE_GANG(gg);          // counted vmcnt via reg deps: 12/8/4/0
        COMPUTE_NODE(0, gg);
        COMPUTE_NODE(1, gg);
    }
    #undef GATHER_GANG
    #undef WRITE_GANG
    #undef COMPUTE_NODE
    __syncthreads();

    // ================= Phase 2: out(32x64) = pre(32x48) @ W^T, waves 0,1 =================
    if (w < 2) {
        const int h = w * 32 + m;

        float16 acc;
        #pragma unroll
        for (int r = 0; r < 16; ++r) acc[r] = 0.f;

        #pragma unroll
        for (int kc = 0; kc < 3; ++kc) {
            const int c0 = kc * 16 + kh8;
            const short8 af = *(const short8*)(pre_s + m * PST + c0);
            const float* wr = W + h * 48 + c0;
            const f32x4 wA = ((const f32x4*)wr)[0];
            const f32x4 wB = ((const f32x4*)wr)[1];
            const short8 bf = mk8(pk(f2bf(wA.x), f2bf(wA.y)), pk(f2bf(wA.z), f2bf(wA.w)),
                                  pk(f2bf(wB.x), f2bf(wB.y)), pk(f2bf(wB.z), f2bf(wB.w)));
            acc = __builtin_amdgcn_mfma_f32_32x32x16_bf16(af, bf, acc, 0, 0, 0);
        }

        #pragma unroll
        for (int r = 0; r < 16; ++r) {
            const int row = (r & 3) + 8 * (r >> 2) + 4 * kh;   // node within block
            __builtin_nontemporal_store(acc[r], &out[(size_t)(base + row) * HH + h]);
        }
    }
}

extern "C" void kernel_launch(void* const* d_in, const int* in_sizes, int n_in,
                              void* d_out, int out_size, void* d_ws, size_t ws_size,
                              hipStream_t stream) {
    const float* x  = (const float*)d_in[0];
    const int*   ei = (const int*)d_in[1];
    const float* kv = (const float*)d_in[2];
    const float* W  = (const float*)d_in[3];
    float* out = (float*)d_out;

    unsigned short* xb = (unsigned short*)d_ws;            // 6.4 MB scratch (padded)
    const int n8 = NN * 8;                                 // 800000 u16x4 chunks
    xcvt<<<(n8 + 255) / 256, 256, 0, stream>>>(x, xb, n8);

    const int grid = NN / NPB;                             // 3125, exact
    gnn<<<grid, TPB, 0, stream>>>(xb, ei, kv, W, out);
}

// Round 6
// 129.814 us; speedup vs baseline: 1.0058x; 1.0058x over previous
//
#include <hip/hip_runtime.h>

// net_86698209837440: N=100000, DEG=32 (edges sorted by tgt, deg==32), D=24, NK=2, H=64.
// R13 = R12 with ds_read_b64_tr_b16 addressing switched to SLOT-GRANULAR
// (interpretation B): per-lane col offset (lane&15)*8 (b64-slot index), group
// (lane>>4)*128, 128B-aligned blocks. R12 (byte-granular col*2) failed absmax
// => falsified. LDS content layout identical in both: per 16-edge region,
// 4x16 edge x feature row-major subtiles:
//   offset(e,f) = ((e>>2)&1)*512 + ((e>>3)&1)*256 + (f>>4)*128 + (e&3)*32 + (f&15)*2
// Writes: same 4 ds_write_b128/gang at remapped wbase (16B chunks contiguous).
// Insurance s_waitcnt lgkmcnt(0) before tr-reads inside the asm block.

#define NN   100000
#define DEG  32
#define EE   (NN * DEG)
#define DD   24
#define HH   64
#define NPB  32            // nodes per block; 100000 = 3125 * 32 exact
#define TPB  256
#define NPW  8             // nodes per wave (4 gangs of 2)
#define PST  56            // pre_s row stride (ushorts)
#define XRU  32            // padded xb row length in u16 (64 bytes)

typedef __attribute__((ext_vector_type(8)))  short short8;
typedef __attribute__((ext_vector_type(16))) float float16;
typedef __attribute__((ext_vector_type(4)))  float f32x4;
typedef __attribute__((ext_vector_type(4)))  int   i32x4;
typedef __attribute__((ext_vector_type(4)))  unsigned short u16x4;

__device__ __forceinline__ unsigned short f2bf(float f) {
    union { float f; unsigned u; } v; v.f = f;
    unsigned r = v.u + 0x7fffu + ((v.u >> 16) & 1u);   // RNE
    return (unsigned short)(r >> 16);
}

__device__ __forceinline__ float bf2f(unsigned u) {
    union { unsigned i; float f; } v; v.i = u << 16; return v.f;
}

// lo16(a) -> low half, lo16(b) -> high half, one v_perm_b32
__device__ __forceinline__ unsigned pk(unsigned a, unsigned b) {
    return __builtin_amdgcn_perm(b, a, 0x05040100u);
}

__device__ __forceinline__ short8 mk8(unsigned u0, unsigned u1, unsigned u2, unsigned u3) {
    union { unsigned u[4]; short8 s; } p;
    p.u[0] = u0; p.u[1] = u1; p.u[2] = u2; p.u[3] = u3;
    return p.s;
}

// ---- pre-pass: x fp32 [N][24] -> bf16 padded [N][32] (64B rows), coalesced
// writes over the full padded table (pad chunks 6,7 write zeros).
__global__ void xcvt(const float* __restrict__ x, unsigned short* __restrict__ xb, int n8) {
    int c = blockIdx.x * blockDim.x + threadIdx.x;   // u16x4 chunk in padded table
    if (c < n8) {
        const int row = c >> 3;
        const int pos = c & 7;
        u16x4 o = (u16x4){0, 0, 0, 0};
        if (pos < 6) {
            f32x4 v = __builtin_nontemporal_load(((const f32x4*)x) + row * 6 + pos);
            o.x = f2bf(v.x); o.y = f2bf(v.y); o.z = f2bf(v.z); o.w = f2bf(v.w);
        }
        ((u16x4*)xb)[c] = o;
    }
}

__global__ __launch_bounds__(TPB, 4) void gnn(
    const unsigned short* __restrict__ xb,   // [N,32] bf16 padded (gather table)
    const int*            __restrict__ ei,   // [2,E]; row 0 = src
    const float*          __restrict__ kv,   // [2,E]
    const float*          __restrict__ W,    // [64,48]
    float*                __restrict__ out)  // [N,64]
{
    __shared__ int            ei_s[NPB * DEG];       // 4 KB: src*64 byte offsets
    __shared__ unsigned short kv_s[2 * NPB * DEG];   // 4 KB bf16 kvals
    __shared__ unsigned short pre_s[NPB * PST];      // 3.5 KB bf16 pre rows
    __shared__ __align__(128) unsigned short xs_s[4][2048];  // 16 KB tr-layout tiles

    const int t    = threadIdx.x;
    const int lane = t & 63;
    const int w    = t >> 6;
    const int m    = lane & 31;      // A-row / B-col / C-col
    const int kh   = lane >> 5;      // K-half
    const int kh8  = kh * 8;
    const int base = blockIdx.x * NPB;
    const int dclamp = (m < DD) ? m : (DD - 1);
    const char* xbc  = (const char*)xb;

    // gang-gather geometry (per lane)
    const int er   = lane >> 2;                        // row-slot within 16
    const int q16  = (lane & 3) * 16;                  // 16B chunk within row
    char* xsb = (char*)&xs_s[w][0];                    // wave-private 4KB tile

    // write remap into tr-native layout: lane holds chunk c=lane&3 of row er.
    const int wbase = ((er >> 2) & 1) * 512 + ((er >> 3) & 1) * 256
                    + (er & 3) * 32
                    + ((lane & 3) >> 1) * 128 + (lane & 1) * 16;
    // tr-read per-lane offset (slot-granular): col slot (lane&15)*8, group (lane>>4)*128
    const int rdoff = (lane & 15) * 8 + (lane >> 4) * 128;
    const unsigned va_base = (unsigned)(size_t)(xsb) + (unsigned)rdoff;

    // ---- cooperative staging: ei row0 (pre-scaled *64) + both kv rows (bf16)
    {
        const size_t eb = (size_t)base * DEG;        // 1024 edges per block
        i32x4 ev = __builtin_nontemporal_load(((const i32x4*)(ei + eb)) + t);
        ev.x <<= 6; ev.y <<= 6; ev.z <<= 6; ev.w <<= 6;
        ((i32x4*)ei_s)[t] = ev;
        const f32x4 c0 = __builtin_nontemporal_load(((const f32x4*)(kv + eb)) + t);
        const f32x4 c1 = __builtin_nontemporal_load(((const f32x4*)(kv + EE + eb)) + t);
        u16x4 u0, u1;
        u0.x = f2bf(c0.x); u0.y = f2bf(c0.y); u0.z = f2bf(c0.z); u0.w = f2bf(c0.w);
        u1.x = f2bf(c1.x); u1.y = f2bf(c1.y); u1.z = f2bf(c1.z); u1.w = f2bf(c1.w);
        ((u16x4*)kv_s)[t] = u0;
        ((u16x4*)(kv_s + NPB * DEG))[t] = u1;
    }
    __syncthreads();

    // ================= Phase 1: full-depth gang pipeline =================
    const unsigned short* kvrow = kv_s + (m & 1) * (NPB * DEG);  // m=0 -> k0, m=1 -> k1

    i32x4 G[4][4];          // 64 VGPR of in-flight gathered lines
    unsigned xv8[NPW];      // epilogue x values, one per node

    // load 64 rows (2 nodes) of gathered x into regs; lanes 4k..4k+3 cover row k
    #define GATHER_GANG(gg) do {                                               \
        const int eb_ = (w * NPW + 2 * (gg)) * DEG;                            \
        const int o0_ = ei_s[eb_ +  0 + er];                                   \
        const int o1_ = ei_s[eb_ + 16 + er];                                   \
        const int o2_ = ei_s[eb_ + 32 + er];                                   \
        const int o3_ = ei_s[eb_ + 48 + er];                                   \
        G[gg][0] = *(const i32x4*)(xbc + (unsigned)(o0_ + q16));               \
        G[gg][1] = *(const i32x4*)(xbc + (unsigned)(o1_ + q16));               \
        G[gg][2] = *(const i32x4*)(xbc + (unsigned)(o2_ + q16));               \
        G[gg][3] = *(const i32x4*)(xbc + (unsigned)(o3_ + q16));               \
    } while (0)

    // write gang tile in tr-native layout: inst k covers 16 edges -> region k*1024
    #define WRITE_GANG(gg) do {                                                \
        *(i32x4*)(xsb + 0 * 1024 + wbase) = G[gg][0];                          \
        *(i32x4*)(xsb + 1 * 1024 + wbase) = G[gg][1];                          \
        *(i32x4*)(xsb + 2 * 1024 + wbase) = G[gg][2];                          \
        *(i32x4*)(xsb + 3 * 1024 + wbase) = G[gg][3];                          \
    } while (0)

    #define COMPUTE_NODE(nn, gg) do {                                          \
        const int nl_ = w * NPW + 2 * (gg) + (nn);                             \
        const unsigned va_ = va_base + (nn) * 2048;                            \
        unsigned long long t0_, t1_, t2_, t3_;                                 \
        asm volatile(                                                          \
            "s_waitcnt lgkmcnt(0)\n\t"                                         \
            "ds_read_b64_tr_b16 %0, %4 offset:0\n\t"                           \
            "ds_read_b64_tr_b16 %1, %4 offset:512\n\t"                         \
            "ds_read_b64_tr_b16 %2, %4 offset:1024\n\t"                        \
            "ds_read_b64_tr_b16 %3, %4 offset:1536\n\t"                        \
            "s_waitcnt lgkmcnt(0)"                                             \
            : "=&v"(t0_), "=&v"(t1_), "=&v"(t2_), "=&v"(t3_)                   \
            : "v"(va_) : "memory");                                            \
        union { unsigned long long q[2]; short8 s; } b0u_, b1u_;               \
        b0u_.q[0] = t0_; b0u_.q[1] = t1_;                                      \
        b1u_.q[0] = t2_; b1u_.q[1] = t3_;                                      \
        const int el_ = nl_ * DEG + kh8;                                       \
        const short8 raw0_ = *(const short8*)(kvrow + el_);                    \
        const short8 raw1_ = *(const short8*)(kvrow + el_ + 16);               \
        const unsigned fill_ = (m == 2) ? 0x3F803F80u : 0u;                    \
        const short8 af0_ = (m < 2) ? raw0_ : mk8(fill_, fill_, fill_, fill_); \
        const short8 af1_ = (m < 2) ? raw1_ : mk8(fill_, fill_, fill_, fill_); \
        float16 acc_;                                                          \
        _Pragma("unroll")                                                      \
        for (int r = 0; r < 16; ++r) acc_[r] = 0.f;                            \
        acc_ = __builtin_amdgcn_mfma_f32_32x32x16_bf16(af0_, b0u_.s, acc_, 0, 0, 0); \
        acc_ = __builtin_amdgcn_mfma_f32_32x32x16_bf16(af1_, b1u_.s, acc_, 0, 0, 0); \
        if (kh == 0 && m < DD) {                                               \
            const float sm_ = acc_[2] * (1.f / 32.f);                          \
            const float pv_ = bf2f(xv8[2 * (gg) + (nn)]) - sm_;                \
            pre_s[nl_ * PST + m]      = f2bf(acc_[0] + pv_);                   \
            pre_s[nl_ * PST + 24 + m] = f2bf(acc_[1] + pv_);                   \
        }                                                                      \
    } while (0)

    // all epilogue xv loads first (oldest in queue -> free by compute time)
    #pragma unroll
    for (int nn = 0; nn < NPW; ++nn)
        xv8[nn] = xb[(size_t)(base + w * NPW + nn) * XRU + dclamp];

    // all 16 gather dwordx4 in flight before any wait
    GATHER_GANG(0);
    GATHER_GANG(1);
    GATHER_GANG(2);
    GATHER_GANG(3);

    #pragma unroll
    for (int gg = 0; gg < NPW / 2; ++gg) {
        WRITE_GANG(gg);          // counted vmcnt via reg deps: 12/8/4/0
        COMPUTE_NODE(0, gg);
        COMPUTE_NODE(1, gg);
    }
    #undef GATHER_GANG
    #undef WRITE_GANG
    #undef COMPUTE_NODE
    __syncthreads();

    // ================= Phase 2: out(32x64) = pre(32x48) @ W^T, waves 0,1 =================
    if (w < 2) {
        const int h = w * 32 + m;

        float16 acc;
        #pragma unroll
        for (int r = 0; r < 16; ++r) acc[r] = 0.f;

        #pragma unroll
        for (int kc = 0; kc < 3; ++kc) {
            const int c0 = kc * 16 + kh8;
            const short8 af = *(const short8*)(pre_s + m * PST + c0);
            const float* wr = W + h * 48 + c0;
            const f32x4 wA = ((const f32x4*)wr)[0];
            const f32x4 wB = ((const f32x4*)wr)[1];
            const short8 bf = mk8(pk(f2bf(wA.x), f2bf(wA.y)), pk(f2bf(wA.z), f2bf(wA.w)),
                                  pk(f2bf(wB.x), f2bf(wB.y)), pk(f2bf(wB.z), f2bf(wB.w)));
            acc = __builtin_amdgcn_mfma_f32_32x32x16_bf16(af, bf, acc, 0, 0, 0);
        }

        #pragma unroll
        for (int r = 0; r < 16; ++r) {
            const int row = (r & 3) + 8 * (r >> 2) + 4 * kh;   // node within block
            __builtin_nontemporal_store(acc[r], &out[(size_t)(base + row) * HH + h]);
        }
    }
}

extern "C" void kernel_launch(void* const* d_in, const int* in_sizes, int n_in,
                              void* d_out, int out_size, void* d_ws, size_t ws_size,
                              hipStream_t stream) {
    const float* x  = (const float*)d_in[0];
    const int*   ei = (const int*)d_in[1];
    const float* kv = (const float*)d_in[2];
    const float* W  = (const float*)d_in[3];
    float* out = (float*)d_out;

    unsigned short* xb = (unsigned short*)d_ws;            // 6.4 MB scratch (padded)
    const int n8 = NN * 8;                                 // 800000 u16x4 chunks
    xcvt<<<(n8 + 255) / 256, 256, 0, stream>>>(x, xb, n8);

    const int grid = NN / NPB;                             // 3125, exact
    gnn<<<grid, TPB, 0, stream>>>(xb, ei, kv, W, out);
}